// Round 4
// baseline (336.278 us; speedup 1.0000x reference)
//
#include <hip/hip_runtime.h>
#include <math.h>

#define N_PRED  12
#define N_DRIFT 2
#define N_DW    3
#define N_NODES 4096
#define BB      128
#define LL      16
#define BN      (BB * N_NODES)   // 524288 pairs
#define TPB     128              // threads (= pairs) per chunk
#define CPB     4                // chunks per block (software pipeline depth)
#define NCHUNK  (BN / TPB)       // 4096 chunks
#define NBLK    (NCHUNK / CPB)   // 1024 blocks = 4 resident/CU, persistent
#define XROW    13               // float4 slots per pair row (12 data + 1 pad)

// ---------------------------------------------------------------------------
// Pre-kernel: fold (deform ∘ conv_t) and (deform ∘ conv_n) into dense uniform
// matrices Mt, Mn of shape [48][12]. Unchanged (verified correct).
// ---------------------------------------------------------------------------
__global__ void deform_precompute(const float* __restrict__ offset_t,
                                  const float* __restrict__ offset_n,
                                  const float* __restrict__ conv_t_w,
                                  const float* __restrict__ conv_n_w,
                                  float* __restrict__ Mt,
                                  float* __restrict__ Mn) {
    int t = threadIdx.x;
    if (t >= N_PRED * N_DW * LL) return;      // 576
    int q  = t % N_PRED;
    int kl = t / N_PRED;
    int k  = kl / LL;
    int l  = kl % LL;

    auto coef = [&](const float* off, int c) -> float {
        float pos = tanhf(off[k * N_PRED + c]) * (float)N_DRIFT
                    + (float)(c + N_DRIFT);
        float idf = floorf(pos);
        float fr  = pos - idf;
        int   id  = (int)idf;
        if (l == id)     return 1.0f - fr;
        if (l == id + 1) return fr;
        return 0.0f;
    };

    float mt = 0.0f;
    #pragma unroll
    for (int h = 0; h < 3; ++h) {
        int c = q - 1 + h;
        if (c < 0 || c >= N_PRED) continue;
        mt += conv_t_w[k * 3 + h] * coef(offset_t, c);
    }

    float mn = 0.0f;
    #pragma unroll
    for (int c = 0; c < N_PRED; ++c) {
        mn += conv_n_w[q * (N_PRED * N_DW) + c * N_DW + k] * coef(offset_n, c);
    }

    Mt[kl * N_PRED + q] = mt;
    Mn[kl * N_PRED + q] = mn;
}

// ---------------------------------------------------------------------------
// Main kernel, R6 = R4 structure (verified correct) + the spill fix.
//
// R4 post-mortem: the 2-deep pipeline (coalesced gload -> regs held across
// compute -> LDS next iter) was right, but VGPR_Count=88 < ~120 live values
// -> the prefetch registers spilled to scratch: 123 MB extra WRITE_SIZE
// (60 regs x 4 B x 131072 threads x 4 iters), +49 MB FETCH. R5 proved the
// IO patterns themselves are clean (FETCH 62 MB / WRITE 24576 KB exact).
//
// Fix: __launch_bounds__(TPB, 2) -> 256-VGPR budget (need ~180). Occupancy
// stays LDS-bound: 38912 B/block -> 4 blocks/CU = 8 waves/CU = 2 waves/SIMD,
// grid 1024 = exactly 4/CU resident, persistent.
//
// Pipeline per chunk: stage regs->LDS (k) | B1 | issue 15 coalesced loads
// (k+1) -> regs | compute k (~3K cy hides HBM latency) | os4 restage | B2 |
// coalesced stores. All IO fully coalesced (1 KB/wave/instr); LDS layouts
// conflict-free (stride-13 x, stride-3 ctrl/out).
// ---------------------------------------------------------------------------
__global__ __launch_bounds__(TPB, 2) void deform_main(
        const float* __restrict__ inp,      // (BN, 3, 16)
        const float* __restrict__ ctrl,     // (BN, 12)
        const float* __restrict__ W,        // (12, 12)
        const float* __restrict__ bparam,   // (N_NODES, 12)
        const float* __restrict__ conv_t_b, // (1,)
        const float* __restrict__ conv_n_b, // (12,)
        const float* __restrict__ Mt,       // (48, 12)
        const float* __restrict__ Mn,       // (48, 12)
        float* __restrict__ out) {          // (BN, 12)
    __shared__ float4 xs4[TPB * XROW];      // 26624 B
    __shared__ float4 cs4[TPB * 3];         //  6144 B
    __shared__ float4 os4[TPB * 3];         //  6144 B   (38912 total)

    const int t      = threadIdx.x;
    const int chunk0 = blockIdx.x * CPB;

    const float4* gin_base = (const float4*)inp;
    const float4* gct_base = (const float4*)ctrl;

    // ---- prologue: chunk 0 into registers (fully coalesced) ----
    float4 pre_x[12];
    float4 pre_c[3];
    {
        const float4* gin = gin_base + (size_t)chunk0 * (TPB * 12);
        #pragma unroll
        for (int i = 0; i < 12; ++i) pre_x[i] = gin[i * TPB + t];
        const float4* gct = gct_base + (size_t)chunk0 * (TPB * 3);
        #pragma unroll
        for (int i = 0; i < 3; ++i) pre_c[i] = gct[i * TPB + t];
    }

    const float ctb = conv_t_b[0];

    #pragma unroll 1
    for (int k = 0; k < CPB; ++k) {
        const int chunk = chunk0 + k;

        // ---- stage: regs -> LDS (waits on this chunk's loads via reg dep) ----
        #pragma unroll
        for (int i = 0; i < 12; ++i) {
            int A = i * TPB + t;            // chunk-local float4 index
            xs4[(A / 12) * XROW + (A % 12)] = pre_x[i];
        }
        #pragma unroll
        for (int i = 0; i < 3; ++i) {
            cs4[i * TPB + t] = pre_c[i];    // stride-3 natural: conflict-free
        }
        __syncthreads();                    // B1

        // ---- issue next chunk's loads NOW; consumed next iteration ----
        if (k + 1 < CPB) {
            const float4* gin = gin_base + (size_t)(chunk + 1) * (TPB * 12);
            #pragma unroll
            for (int i = 0; i < 12; ++i) pre_x[i] = gin[i * TPB + t];
            const float4* gct = gct_base + (size_t)(chunk + 1) * (TPB * 3);
            #pragma unroll
            for (int i = 0; i < 3; ++i) pre_c[i] = gct[i * TPB + t];
        }

        const int tid = chunk * TPB + t;
        const int n   = tid & (N_NODES - 1);

        // ---- gate accumulator starts at bparam[n] (192 KB, L2-resident) ----
        float accg[12];
        {
            const float* bp = bparam + (size_t)n * N_PRED;
            #pragma unroll
            for (int i = 0; i < 3; ++i) {
                float4 v = *(const float4*)(bp + 4 * i);
                accg[4 * i + 0] = v.x; accg[4 * i + 1] = v.y;
                accg[4 * i + 2] = v.z; accg[4 * i + 3] = v.w;
            }
        }

        // ---- pred_t / pred_n accumulators (biases) ----
        float acct[12], accn[12];
        #pragma unroll
        for (int q = 0; q < N_PRED; ++q) {
            acct[q] = ctb;
            accn[q] = conv_n_b[q];
        }

        // ---- folded matvecs: 1152 FMAs, weights wave-uniform (s_load) ----
        #pragma unroll
        for (int c = 0; c < 12; ++c) {
            float4 v = xs4[t * XROW + c];   // conflict-free b128 (13 coprime 8)
            #pragma unroll
            for (int e = 0; e < 4; ++e) {
                float xv = (e == 0) ? v.x : (e == 1) ? v.y : (e == 2) ? v.z : v.w;
                const int kl = 4 * c + e;
                #pragma unroll
                for (int q = 0; q < N_PRED; ++q) {
                    acct[q] = fmaf(Mt[kl * N_PRED + q], xv, acct[q]);
                    accn[q] = fmaf(Mn[kl * N_PRED + q], xv, accn[q]);
                }
            }
        }

        // ---- gate matvec (ctrl from LDS, stride-3: conflict-free) ----
        float cr[12];
        #pragma unroll
        for (int i = 0; i < 3; ++i) {
            float4 v = cs4[t * 3 + i];
            cr[4 * i + 0] = v.x; cr[4 * i + 1] = v.y;
            cr[4 * i + 2] = v.z; cr[4 * i + 3] = v.w;
        }
        #pragma unroll
        for (int p = 0; p < N_PRED; ++p) {
            float cv = cr[p];
            #pragma unroll
            for (int q = 0; q < N_PRED; ++q) {
                accg[q] = fmaf(cv, W[p * N_PRED + q], accg[q]);
            }
        }

        // ---- sigmoid gate + blend ----
        float4 o4[3];
        float* ov = (float*)o4;
        #pragma unroll
        for (int q = 0; q < N_PRED; ++q) {
            float g = 1.0f / (1.0f + __expf(-accg[q]));
            ov[q] = accn[q] * g + acct[q] * (1.0f - g);
        }

        // ---- restage outputs: own slots (no cross-thread hazard pre-B2) ----
        #pragma unroll
        for (int j = 0; j < 3; ++j) {
            os4[t * 3 + j] = o4[j];         // quad (3t+j)%8: conflict-free
        }
        __syncthreads();                    // B2

        // ---- fully-coalesced 1 KB/instr stores ----
        float4* gout = (float4*)out + (size_t)chunk * (TPB * 3);
        #pragma unroll
        for (int j = 0; j < 3; ++j) {
            int A = j * TPB + t;
            gout[A] = os4[A];
        }
        // next iter's B1 separates these os4 reads from the next os4 writes
    }
}

extern "C" void kernel_launch(void* const* d_in, const int* in_sizes, int n_in,
                              void* d_out, int out_size, void* d_ws, size_t ws_size,
                              hipStream_t stream) {
    const float* inp      = (const float*)d_in[0];
    const float* ctrl     = (const float*)d_in[1];
    const float* offset_t = (const float*)d_in[2];
    const float* offset_n = (const float*)d_in[3];
    const float* conv_t_w = (const float*)d_in[4];
    const float* conv_t_b = (const float*)d_in[5];
    const float* conv_n_w = (const float*)d_in[6];
    const float* conv_n_b = (const float*)d_in[7];
    const float* W        = (const float*)d_in[8];
    const float* bparam   = (const float*)d_in[9];
    float* out = (float*)d_out;

    float* Mt = (float*)d_ws;            // 576 floats
    float* Mn = Mt + N_DW * LL * N_PRED; // 576 floats (ws >= 4608 B)

    deform_precompute<<<1, 576, 0, stream>>>(offset_t, offset_n,
                                             conv_t_w, conv_n_w, Mt, Mn);
    deform_main<<<NBLK, TPB, 0, stream>>>(inp, ctrl, W, bparam,
                                          conv_t_b, conv_n_b, Mt, Mn, out);
}

// Round 5
// 198.675 us; speedup vs baseline: 1.6926x; 1.6926x over previous
//
#include <hip/hip_runtime.h>
#include <math.h>

#define N_PRED  12
#define N_DRIFT 2
#define N_DW    3
#define N_NODES 4096
#define BB      128
#define LL      16
#define BN      (BB * N_NODES)   // 524288 pairs
#define TPB     128              // 2 waves; each wave owns 64 pairs
#define NBLK    (BN / TPB)       // 4096 blocks
#define XROW    13               // float4 slots per pair row (12 data + 1 pad)
#define WROW    (64 * XROW)      // 832 float4 slots per wave region

// ---------------------------------------------------------------------------
// Pre-kernel: fold (deform ∘ conv_t) and (deform ∘ conv_n) into dense uniform
// matrices Mt, Mn of shape [48][12]. Unchanged (verified correct).
// ---------------------------------------------------------------------------
__global__ void deform_precompute(const float* __restrict__ offset_t,
                                  const float* __restrict__ offset_n,
                                  const float* __restrict__ conv_t_w,
                                  const float* __restrict__ conv_n_w,
                                  float* __restrict__ Mt,
                                  float* __restrict__ Mn) {
    int t = threadIdx.x;
    if (t >= N_PRED * N_DW * LL) return;      // 576
    int q  = t % N_PRED;
    int kl = t / N_PRED;
    int k  = kl / LL;
    int l  = kl % LL;

    auto coef = [&](const float* off, int c) -> float {
        float pos = tanhf(off[k * N_PRED + c]) * (float)N_DRIFT
                    + (float)(c + N_DRIFT);
        float idf = floorf(pos);
        float fr  = pos - idf;
        int   id  = (int)idf;
        if (l == id)     return 1.0f - fr;
        if (l == id + 1) return fr;
        return 0.0f;
    };

    float mt = 0.0f;
    #pragma unroll
    for (int h = 0; h < 3; ++h) {
        int c = q - 1 + h;
        if (c < 0 || c >= N_PRED) continue;
        mt += conv_t_w[k * 3 + h] * coef(offset_t, c);
    }

    float mn = 0.0f;
    #pragma unroll
    for (int c = 0; c < N_PRED; ++c) {
        mn += conv_n_w[q * (N_PRED * N_DW) + c * N_DW + k] * coef(offset_n, c);
    }

    Mt[kl * N_PRED + q] = mt;
    Mn[kl * N_PRED + q] = mn;
}

// ---------------------------------------------------------------------------
// Main kernel, R7: barrier-free wave-private blocks.
//
// Post-mortems distilled: (R3) scattered stores/loads amplify HBM 5x;
// (R4/R6) >~50 prefetch VGPRs live across compute ALWAYS spill (allocator
// caps at 88 regardless of launch bounds); (R5) 4 waves/CU cannot hide
// latency; (R2 baseline) VALUBusy 17% at 10 waves/CU => the cost is
// serialization (load stall + 2 barriers convoying the block), not BW.
//
// R7 removes every serializer that doesn't need new machinery:
//  - each WAVE owns 64 pairs end-to-end: its stage region, its 64 stride-13
//    rows, its output restage region. No __syncthreads in the kernel at all;
//    same-wave DS ops are in-order (R5-verified os restage pattern), and
//    waves drift freely so their memory phases decorrelate.
//  - ctrl+bparam: per-thread register loads (24 VGPRs) issued after staging,
//    consumed at the gate ~2600 cy later (hidden under matvec). cs4 dropped.
//  - LDS = 26624 B -> 6 blocks/CU = 12 waves/CU (vs R2's 10). Peak live
//    ~75 VGPR (stage: 48 + addressing) -> under the 88 wall, no spills.
//  - outputs reuse the wave's own x region after the x reads (same-wave
//    WAR through the DS FIFO): coalesced 1 KB stores, zero extra LDS.
// All global IO is 1 KB/wave/instr lane-linear; all LDS ops conflict-free
// in groups-of-8 (stride 13 and 3 both coprime to 8).
// ---------------------------------------------------------------------------
__global__ __launch_bounds__(TPB) void deform_main(
        const float* __restrict__ inp,      // (BN, 3, 16)
        const float* __restrict__ ctrl,     // (BN, 12)
        const float* __restrict__ W,        // (12, 12)
        const float* __restrict__ bparam,   // (N_NODES, 12)
        const float* __restrict__ conv_t_b, // (1,)
        const float* __restrict__ conv_n_b, // (12,)
        const float* __restrict__ Mt,       // (48, 12)
        const float* __restrict__ Mn,       // (48, 12)
        float* __restrict__ out) {          // (BN, 12)
    __shared__ float4 xs4[TPB * XROW];      // 26624 B total; [w*WROW..] per wave

    const int t    = threadIdx.x;
    const int l    = t & 63;                // lane
    const int w    = t >> 6;                // wave (0/1)
    const int base = w * WROW;              // wave-private LDS base (float4)

    // ---- 12 coalesced 1 KB x loads: wave w covers block float4s
    //      [w*768, w*768+768) = its own 64 pairs' rows ----
    const float4* gin = (const float4*)inp + (size_t)blockIdx.x * (TPB * 12)
                        + w * 768;
    float4 pre[12];
    #pragma unroll
    for (int i = 0; i < 12; ++i) pre[i] = gin[i * 64 + l];

    // ---- stage to stride-13 rows (wave-local transpose) ----
    #pragma unroll
    for (int i = 0; i < 12; ++i) {
        int A = i * 64 + l;                 // wave-local float4 idx 0..767
        xs4[base + (A / 12) * XROW + (A % 12)] = pre[i];
    }

    // ---- issue ctrl + bparam register loads NOW; consumed at the gate
    //      (~2600 cy later) so their latency hides under the matvec ----
    const int tid = blockIdx.x * TPB + t;
    const int n   = tid & (N_NODES - 1);
    float4 cv[3], bv[3];
    {
        const float4* gct = (const float4*)ctrl + (size_t)tid * 3;
        #pragma unroll
        for (int i = 0; i < 3; ++i) cv[i] = gct[i];
        const float4* gbp = (const float4*)bparam + (size_t)n * 3;
        #pragma unroll
        for (int i = 0; i < 3; ++i) bv[i] = gbp[i];
    }

    // ---- pred_t / pred_n accumulators (biases) ----
    float acct[12], accn[12];
    const float ctb = conv_t_b[0];
    #pragma unroll
    for (int q = 0; q < N_PRED; ++q) {
        acct[q] = ctb;
        accn[q] = conv_n_b[q];
    }

    // ---- folded matvecs: 1152 FMAs, weights wave-uniform (s_load);
    //      x read from own row: quads (13l+c) distinct mod 8 per 8-lane
    //      group -> conflict-free b128 ----
    #pragma unroll
    for (int c = 0; c < 12; ++c) {
        float4 v = xs4[base + l * XROW + c];
        #pragma unroll
        for (int e = 0; e < 4; ++e) {
            float xv = (e == 0) ? v.x : (e == 1) ? v.y : (e == 2) ? v.z : v.w;
            const int kl = 4 * c + e;
            #pragma unroll
            for (int q = 0; q < N_PRED; ++q) {
                acct[q] = fmaf(Mt[kl * N_PRED + q], xv, acct[q]);
                accn[q] = fmaf(Mn[kl * N_PRED + q], xv, accn[q]);
            }
        }
    }

    // ---- gate matvec (ctrl/bparam from registers) ----
    float accg[12];
    const float* bvf = (const float*)bv;
    const float* cvf = (const float*)cv;
    #pragma unroll
    for (int q = 0; q < N_PRED; ++q) accg[q] = bvf[q];
    #pragma unroll
    for (int p = 0; p < N_PRED; ++p) {
        float cval = cvf[p];
        #pragma unroll
        for (int q = 0; q < N_PRED; ++q) {
            accg[q] = fmaf(cval, W[p * N_PRED + q], accg[q]);
        }
    }

    // ---- sigmoid gate + blend ----
    float4 o4[3];
    float* ov = (float*)o4;
    #pragma unroll
    for (int q = 0; q < N_PRED; ++q) {
        float g = 1.0f / (1.0f + __expf(-accg[q]));
        ov[q] = accn[q] * g + acct[q] * (1.0f - g);
    }

    // ---- output restage into own wave's x region (x reads are earlier
    //      same-wave DS ops -> in-order WAR, no barrier needed) ----
    #pragma unroll
    for (int j = 0; j < 3; ++j) {
        xs4[base + 3 * l + j] = o4[j];      // quads 3l+j distinct mod 8 / group
    }
    // ---- coalesced 1 KB stores ----
    float4* gout = (float4*)out + (size_t)blockIdx.x * (TPB * 3) + w * 192;
    #pragma unroll
    for (int j = 0; j < 3; ++j) {
        gout[j * 64 + l] = xs4[base + j * 64 + l];
    }
}

extern "C" void kernel_launch(void* const* d_in, const int* in_sizes, int n_in,
                              void* d_out, int out_size, void* d_ws, size_t ws_size,
                              hipStream_t stream) {
    const float* inp      = (const float*)d_in[0];
    const float* ctrl     = (const float*)d_in[1];
    const float* offset_t = (const float*)d_in[2];
    const float* offset_n = (const float*)d_in[3];
    const float* conv_t_w = (const float*)d_in[4];
    const float* conv_t_b = (const float*)d_in[5];
    const float* conv_n_w = (const float*)d_in[6];
    const float* conv_n_b = (const float*)d_in[7];
    const float* W        = (const float*)d_in[8];
    const float* bparam   = (const float*)d_in[9];
    float* out = (float*)d_out;

    float* Mt = (float*)d_ws;            // 576 floats
    float* Mn = Mt + N_DW * LL * N_PRED; // 576 floats (ws >= 4608 B)

    deform_precompute<<<1, 576, 0, stream>>>(offset_t, offset_n,
                                             conv_t_w, conv_n_w, Mt, Mn);
    deform_main<<<NBLK, TPB, 0, stream>>>(inp, ctrl, W, bparam,
                                          conv_t_b, conv_n_b, Mt, Mn, out);
}